// Round 1
// baseline (4426.441 us; speedup 1.0000x reference)
//
#include <hip/hip_runtime.h>
#include <hip/hip_bf16.h>
#include <cstdint>

// ---------- types ----------
typedef __attribute__((ext_vector_type(8))) short bf16x8;          // MFMA A/B frag (8 bf16)
typedef __attribute__((ext_vector_type(8))) unsigned short ushort8;
typedef __attribute__((ext_vector_type(4))) float f32x4;           // MFMA C/D frag

__device__ __forceinline__ unsigned short f2bf(float f) {
    unsigned u = __builtin_bit_cast(unsigned, f);
    u += 0x7FFFu + ((u >> 16) & 1u);     // RNE
    return (unsigned short)(u >> 16);
}
__device__ __forceinline__ float bf2f(unsigned short s) {
    unsigned u = ((unsigned)s) << 16;
    return __builtin_bit_cast(float, u);
}

// ---------- f32 -> bf16 weight conversion ----------
__global__ __launch_bounds__(256) void cvt_w(const float* __restrict__ s,
                                             unsigned short* __restrict__ d, int n4) {
    int i = blockIdx.x * 256 + threadIdx.x;
    if (i >= n4) return;
    float4 v = ((const float4*)s)[i];
    ushort4 o = make_ushort4(f2bf(v.x), f2bf(v.y), f2bf(v.z), f2bf(v.w));
    ((ushort4*)d)[i] = o;
}

// ---------- LayerNorm (f32 in) -> bf16 out, one block per row, C=1024 ----------
__global__ __launch_bounds__(256) void ln_bf16(const float* __restrict__ x,
                                               const float* __restrict__ g,
                                               const float* __restrict__ bta,
                                               unsigned short* __restrict__ out) {
    const int row = blockIdx.x;
    const int t = threadIdx.x;
    const float4 v = ((const float4*)(x + (size_t)row * 1024))[t];
    float s  = v.x + v.y + v.z + v.w;
    float ss = v.x*v.x + v.y*v.y + v.z*v.z + v.w*v.w;
#pragma unroll
    for (int off = 32; off > 0; off >>= 1) {
        s  += __shfl_down(s,  off, 64);
        ss += __shfl_down(ss, off, 64);
    }
    __shared__ float red[8];
    if ((t & 63) == 0) { red[t >> 6] = s; red[4 + (t >> 6)] = ss; }
    __syncthreads();
    const float S  = red[0] + red[1] + red[2] + red[3];
    const float SS = red[4] + red[5] + red[6] + red[7];
    const float mu = S * (1.0f / 1024.0f);
    const float rs = rsqrtf(SS * (1.0f / 1024.0f) - mu * mu + 1e-5f);
    const float4 gv = ((const float4*)g)[t];
    const float4 bv = ((const float4*)bta)[t];
    ushort4 o = make_ushort4(f2bf((v.x - mu) * rs * gv.x + bv.x),
                             f2bf((v.y - mu) * rs * gv.y + bv.y),
                             f2bf((v.z - mu) * rs * gv.z + bv.z),
                             f2bf((v.w - mu) * rs * gv.w + bv.w));
    ((ushort4*)(out + (size_t)row * 1024))[t] = o;
}

// ---------- GEMM: C[M,N] = A[M,K](bf16) @ W[N,K](bf16)^T + bias, fused epilogue ----------
// MODE 0: out bf16 = acc + bias
// MODE 1: out f32  = res + acc + bias
// MODE 2: out bf16 = gelu_tanh(acc + bias)
// 128x128 tile, BK=32, 256 threads (4 waves, 2x2), 4x4 MFMA 16x16x32 per wave.
template <int MODE>
__global__ __launch_bounds__(256) void gemm_bt(const unsigned short* __restrict__ A,
                                               const unsigned short* __restrict__ W,
                                               const float* __restrict__ bias,
                                               const float* __restrict__ res,
                                               void* __restrict__ outv,
                                               int N, int K) {
    __shared__ __align__(16) unsigned short lA[128 * 32];  // 8 KB
    __shared__ __align__(16) unsigned short lB[128 * 32];  // 8 KB
    const int t = threadIdx.x;
    const int lane = t & 63;
    const int wave = t >> 6;
    const int wm = wave >> 1, wn = wave & 1;
    const long row0 = (long)blockIdx.y * 128;
    const long col0 = (long)blockIdx.x * 128;

    // staging: thread t owns 16B chunks t and t+256 of each 128x32 tile
    const unsigned short* gA0 = A + (row0 + (t >> 2)) * (long)K + (t & 3) * 8;
    const unsigned short* gA1 = gA0 + 64L * K;
    const unsigned short* gW0 = W + (col0 + (t >> 2)) * (long)K + (t & 3) * 8;
    const unsigned short* gW1 = gW0 + 64L * K;

    f32x4 acc[4][4] = {};
    const int arow = lane & 15;          // A: m index / B: n index
    const int koff = (lane >> 4) * 8;    // k offset within 32

    for (int kk = 0; kk < K; kk += 32) {
        ushort8 a0 = *(const ushort8*)(gA0 + kk);
        ushort8 a1 = *(const ushort8*)(gA1 + kk);
        ushort8 w0 = *(const ushort8*)(gW0 + kk);
        ushort8 w1 = *(const ushort8*)(gW1 + kk);
        __syncthreads();  // prev iter's frag reads done
        *(ushort8*)&lA[t * 8]        = a0;
        *(ushort8*)&lA[2048 + t * 8] = a1;
        *(ushort8*)&lB[t * 8]        = w0;
        *(ushort8*)&lB[2048 + t * 8] = w1;
        __syncthreads();
        bf16x8 af[4], bfr[4];
#pragma unroll
        for (int i = 0; i < 4; i++)
            af[i] = *(const bf16x8*)&lA[(wm * 64 + i * 16 + arow) * 32 + koff];
#pragma unroll
        for (int j = 0; j < 4; j++)
            bfr[j] = *(const bf16x8*)&lB[(wn * 64 + j * 16 + arow) * 32 + koff];
#pragma unroll
        for (int i = 0; i < 4; i++)
#pragma unroll
            for (int j = 0; j < 4; j++)
                acc[i][j] = __builtin_amdgcn_mfma_f32_16x16x32_bf16(af[i], bfr[j], acc[i][j], 0, 0, 0);
    }

    // epilogue: C/D layout col=lane&15, row=(lane>>4)*4+r
    const int r4 = (lane >> 4) * 4;
#pragma unroll
    for (int j = 0; j < 4; j++) {
        const long col = col0 + wn * 64 + j * 16 + (lane & 15);
        const float bj = bias[col];
#pragma unroll
        for (int i = 0; i < 4; i++) {
#pragma unroll
            for (int r = 0; r < 4; r++) {
                const long row = row0 + wm * 64 + i * 16 + r4 + r;
                float val = acc[i][j][r] + bj;
                if (MODE == 2) {
                    float u = 1.5957691216057308f * (val + 0.044715f * val * val * val); // 2*sqrt(2/pi)*(...)
                    float e = __expf(u);                       // e^{2y}
                    float th = 1.0f - 2.0f / (e + 1.0f);       // tanh(y), NaN-safe
                    val = 0.5f * val * (1.0f + th);
                }
                if (MODE == 1) {
                    ((float*)outv)[row * N + col] = res[row * N + col] + val;
                } else {
                    ((unsigned short*)outv)[row * N + col] = f2bf(val);
                }
            }
        }
    }
}

// ---------- attention: one block per (b,h); N=65, D=64 ----------
// qkv [B*65, 3072] bf16 (q|k|v each 1024 = 16 heads * 64)
// o   [B*65, 1024] bf16
#define SSTR 68  // f32 row stride for q,k (16B-aligned, bank-spread for i-fast access)
__global__ __launch_bounds__(256) void attn(const unsigned short* __restrict__ qkv,
                                            const float* __restrict__ abias,
                                            const float* __restrict__ bscale_p,
                                            unsigned short* __restrict__ o) {
    const int bh = blockIdx.x;
    const int b = bh >> 4, h = bh & 15;
    const int t = threadIdx.x;
    __shared__ __align__(16) float sq[65 * SSTR];           // 17.7 KB
    __shared__ __align__(16) float sk[65 * SSTR];           // 17.7 KB
    __shared__ __align__(16) unsigned short sv[65 * SSTR];  // 8.8 KB (bf16)
    __shared__ float ss[65 * 65];                            // 16.9 KB
    const size_t base = (size_t)b * 65 * 3072 + h * 64;
    for (int idx = t; idx < 65 * 64; idx += 256) {
        int n = idx >> 6, d = idx & 63;
        size_t g = base + (size_t)n * 3072 + d;
        sq[n * SSTR + d] = bf2f(qkv[g]);
        sk[n * SSTR + d] = bf2f(qkv[g + 1024]);
        sv[n * SSTR + d] = qkv[g + 2048];
    }
    __syncthreads();
    const float bs = bscale_p[0];
    const float* bias_h = abias + h * 65 * 65;
    // scores: i-fast so q reads are bank-spread, k reads are wave broadcasts
    for (int p = t; p < 65 * 65; p += 256) {
        int i = p % 65, j = p / 65;
        const float4* q4 = (const float4*)&sq[i * SSTR];
        const float4* k4 = (const float4*)&sk[j * SSTR];
        float ax = 0.f, ay = 0.f, az = 0.f, aw = 0.f;
#pragma unroll
        for (int c = 0; c < 16; c++) {
            float4 a = q4[c], bb = k4[c];
            ax += a.x * bb.x; ay += a.y * bb.y; az += a.z * bb.z; aw += a.w * bb.w;
        }
        ss[i * 65 + j] = (ax + ay + az + aw) * 0.125f + bs * bias_h[i * 65 + j];
    }
    __syncthreads();
    if (t < 65) {  // softmax over j, one row per thread
        float* r = &ss[t * 65];
        float m = -1e30f;
        for (int j = 0; j < 65; j++) m = fmaxf(m, r[j]);
        float sum = 0.f;
        for (int j = 0; j < 65; j++) { float e = __expf(r[j] - m); r[j] = e; sum += e; }
        float inv = 1.0f / sum;
        for (int j = 0; j < 65; j++) r[j] *= inv;
    }
    __syncthreads();
    // o[i][d4*4..+3] : i-fast (ss reads bank-spread, v reads broadcast)
    for (int p = t; p < 65 * 16; p += 256) {
        int i = p % 65, d4 = p / 65;
        float ax = 0.f, ay = 0.f, az = 0.f, aw = 0.f;
        for (int j = 0; j < 65; j++) {
            float pv = ss[i * 65 + j];
            ushort4 vv = *(const ushort4*)&sv[j * SSTR + d4 * 4];
            ax += pv * bf2f(vv.x); ay += pv * bf2f(vv.y);
            az += pv * bf2f(vv.z); aw += pv * bf2f(vv.w);
        }
        size_t go = (size_t)(b * 65 + i) * 1024 + h * 64 + d4 * 4;
        *(ushort4*)&o[go] = make_ushort4(f2bf(ax), f2bf(ay), f2bf(az), f2bf(aw));
    }
}

// ---------- driver ----------
extern "C" void kernel_launch(void* const* d_in, const int* in_sizes, int n_in,
                              void* d_out, int out_size, void* d_ws, size_t ws_size,
                              hipStream_t stream) {
    const float* x      = (const float*)d_in[0];
    const float* ln1_g  = (const float*)d_in[1];
    const float* ln1_b  = (const float*)d_in[2];
    const float* qkv_w  = (const float*)d_in[3];
    const float* qkv_b  = (const float*)d_in[4];
    const float* proj_w = (const float*)d_in[5];
    const float* proj_b = (const float*)d_in[6];
    const float* abias  = (const float*)d_in[7];
    const float* bscale = (const float*)d_in[8];
    const float* ln2_g  = (const float*)d_in[9];
    const float* ln2_b  = (const float*)d_in[10];
    const float* fc1_w  = (const float*)d_in[11];
    const float* fc1_b  = (const float*)d_in[12];
    const float* fc2_w  = (const float*)d_in[13];
    const float* fc2_b  = (const float*)d_in[14];
    float* out = (float*)d_out;

    // workspace layout (bytes):
    //   [0, 545259520)            qkv bf16 [66560,3072] -> reused as h3 bf16 [66560,4096]
    //   [545259520, 681574400)    hbuf bf16 [66560,1024]: h1 -> o -> h2
    //   [681574400, ...)          bf16 weights: qkv_w, proj_w, fc1_w, fc2_w
    char* ws = (char*)d_ws;
    unsigned short* qkvbuf = (unsigned short*)(ws);
    unsigned short* hbuf   = (unsigned short*)(ws + 545259520ULL);
    unsigned short* wqkv   = (unsigned short*)(ws + 681574400ULL);
    unsigned short* wproj  = (unsigned short*)(ws + 687865856ULL);
    unsigned short* wfc1   = (unsigned short*)(ws + 689963008ULL);
    unsigned short* wfc2   = (unsigned short*)(ws + 698351616ULL);

    const int M = 66560;  // B*N = 1024*65, = 520*128

    cvt_w<<<3072, 256, 0, stream>>>(qkv_w,  wqkv,  786432);
    cvt_w<<<1024, 256, 0, stream>>>(proj_w, wproj, 262144);
    cvt_w<<<4096, 256, 0, stream>>>(fc1_w,  wfc1,  1048576);
    cvt_w<<<4096, 256, 0, stream>>>(fc2_w,  wfc2,  1048576);

    ln_bf16<<<M, 256, 0, stream>>>(x, ln1_g, ln1_b, hbuf);                       // h1
    gemm_bt<0><<<dim3(24, 520), 256, 0, stream>>>(hbuf, wqkv, qkv_b, nullptr,
                                                  (void*)qkvbuf, 3072, 1024);    // qkv
    attn<<<16384, 256, 0, stream>>>(qkvbuf, abias, bscale, hbuf);                // o
    gemm_bt<1><<<dim3(8, 520), 256, 0, stream>>>(hbuf, wproj, proj_b, x,
                                                 (void*)out, 1024, 1024);        // x2 = x + proj(o)
    ln_bf16<<<M, 256, 0, stream>>>(out, ln2_g, ln2_b, hbuf);                     // h2
    gemm_bt<2><<<dim3(32, 520), 256, 0, stream>>>(hbuf, wfc1, fc1_b, nullptr,
                                                  (void*)qkvbuf, 4096, 1024);    // h3 = gelu(fc1)
    gemm_bt<1><<<dim3(8, 520), 256, 0, stream>>>(qkvbuf, wfc2, fc2_b, out,
                                                 (void*)out, 1024, 4096);        // out = x2 + fc2(h3)
}